// Round 10
// baseline (138.506 us; speedup 1.0000x reference)
//
#include <hip/hip_runtime.h>
#include <hip/hip_bf16.h>
#include <math.h>

// Problem constants (B=1)
#define SEQ   2048
#define HID   1024
#define NH    16
#define HD    64
#define WIN   128
#define GSTR  64
#define NSPL  8     // key-range splits (8 best: 16 regressed +6.5us, R7)

typedef __attribute__((ext_vector_type(8))) short short8;   // 8 bf16 = 4 VGPRs
typedef __attribute__((ext_vector_type(4))) float f32x4;    // MFMA C/D
typedef unsigned short ushort_t;

// RNE fp32 -> bf16 bits (finite inputs)
__device__ inline unsigned short bf16b(float f) {
    union { float f; unsigned int u; } v; v.f = f;
    return (unsigned short)((v.u + 0x7FFFu + ((v.u >> 16) & 1u)) >> 16);
}

#define GLOAD_LDS16(gp, lp)                                                    \
    __builtin_amdgcn_global_load_lds(                                          \
        (const __attribute__((address_space(1))) unsigned int*)(gp),           \
        (__attribute__((address_space(3))) unsigned int*)(lp), 16, 0, 0)

// ---------------------------------------------------------------------------
// fp32 -> bf16 pre-convert of x, Wqkv, Wout
// ---------------------------------------------------------------------------
__global__ __launch_bounds__(256) void cvt_bf16(const float4* __restrict__ x,
                                                const float4* __restrict__ wq,
                                                const float4* __restrict__ wo,
                                                ushort4* __restrict__ x16,
                                                ushort4* __restrict__ wq16,
                                                ushort4* __restrict__ wo16) {
    for (int idx = blockIdx.x * 256 + threadIdx.x; idx < 1572864;
         idx += gridDim.x * 256) {
        const float4* src; ushort4* dst; int off;
        if (idx < 524288)       { src = x;  dst = x16;  off = idx; }
        else if (idx < 1310720) { src = wq; dst = wq16; off = idx - 524288; }
        else                    { src = wo; dst = wo16; off = idx - 1310720; }
        float4 v = src[off];
        ushort4 o;
        o.x = bf16b(v.x); o.y = bf16b(v.y); o.z = bf16b(v.z); o.w = bf16b(v.w);
        dst[off] = o;
    }
}

// ---------------------------------------------------------------------------
// MFMA GEMM: C[M,N] = A[M,K] @ B[N,K]^T, bf16 in, fp32 acc.
// BK=128, 2-barrier/K-step (best-measured schedule; pipelining/tile variants
// all null or worse — R3-R8 ledger).
// R9: NW=8 QKV (24 waves/CU) measured -1.2us — TLP covers the vmcnt(0)
// barrier drain. R10: same lever on the out-GEMM (was 8 waves/CU = 2/SIMD,
// the lowest-occupancy kernel in the program -> 16 waves/CU).
// NW=4 reproduces the original R4 mapping exactly.
// R6 lesson: NO device-scope fences in hot kernels (+43us on 8 XCDs).
// ---------------------------------------------------------------------------
template <int BM, int BN, int BK, int NW, typename OT>
__global__ __launch_bounds__(NW * 64) void gemm_bt16(const unsigned short* __restrict__ A,
                                                     const unsigned short* __restrict__ B,
                                                     OT* __restrict__ C,
                                                     int M, int N, int K) {
    constexpr int WMW = 2;                 // waves along M
    constexpr int WNW = NW / 2;            // waves along N
    constexpr int MI = (BM / WMW) / 16;    // 16-row frags per wave
    constexpr int NJ = (BN / WNW) / 16;    // 16-col frags per wave
    constexpr int NP = BK / 32;            // 32-col panels per K-step
    __shared__ unsigned short As[NP][BM * 32];
    __shared__ unsigned short Bs[NP][BN * 32];

    const int tid  = threadIdx.x;
    const int wave = tid >> 6;
    const int lane = tid & 63;
    const int quad = lane >> 4;
    const int l15  = lane & 15;
    const int bm = blockIdx.y * BM;
    const int bn = blockIdx.x * BN;
    const int wm = (wave % WMW) * (BM / WMW);
    const int wn = (wave / WMW) * (BN / WNW);
    const int srow = lane >> 2;
    const int scol = (lane & 3) * 8;

    f32x4 acc[MI][NJ];
    #pragma unroll
    for (int i = 0; i < MI; ++i)
        #pragma unroll
        for (int j = 0; j < NJ; ++j)
            acc[i][j] = (f32x4){0.f, 0.f, 0.f, 0.f};

    for (int k0 = 0; k0 < K; k0 += BK) {
        // stage: flat unit loop; unit = (panel hh, 16-row group rg)
        #pragma unroll
        for (int u = wave; u < NP * (BM / 16); u += NW) {
            const int hh = u / (BM / 16);
            const int rg = u % (BM / 16);
            const int row = rg * 16 + srow;
            GLOAD_LDS16(A + (size_t)(bm + row) * K + k0 + hh * 32 + scol,
                        &As[hh][(size_t)row * 32 + scol]);
        }
        #pragma unroll
        for (int u = wave; u < NP * (BN / 16); u += NW) {
            const int hh = u / (BN / 16);
            const int rg = u % (BN / 16);
            const int row = rg * 16 + srow;
            GLOAD_LDS16(B + (size_t)(bn + row) * K + k0 + hh * 32 + scol,
                        &Bs[hh][(size_t)row * 32 + scol]);
        }
        __syncthreads();

        #pragma unroll
        for (int hh = 0; hh < NP; ++hh) {
            short8 a[MI], b[NJ];
            #pragma unroll
            for (int im = 0; im < MI; ++im)
                a[im] = *(const short8*)&As[hh][(wm + im * 16 + l15) * 32 + quad * 8];
            #pragma unroll
            for (int jn = 0; jn < NJ; ++jn)
                b[jn] = *(const short8*)&Bs[hh][(wn + jn * 16 + l15) * 32 + quad * 8];

            #pragma unroll
            for (int im = 0; im < MI; ++im)
                #pragma unroll
                for (int jn = 0; jn < NJ; ++jn)
                    acc[im][jn] = __builtin_amdgcn_mfma_f32_16x16x32_bf16(
                        b[jn], a[im], acc[im][jn], 0, 0, 0);
        }
        __syncthreads();
    }

    // Epilogue: lane holds C[r = ...+l15][c = ...+quad*4 + (0..3)] -> vector store
    #pragma unroll
    for (int im = 0; im < MI; ++im)
        #pragma unroll
        for (int jn = 0; jn < NJ; ++jn) {
            const int r = bm + wm + im * 16 + l15;
            const int c = bn + wn + jn * 16 + quad * 4;
            if constexpr (sizeof(OT) == 2) {
                ushort4 o;
                o.x = bf16b(acc[im][jn][0]);
                o.y = bf16b(acc[im][jn][1]);
                o.z = bf16b(acc[im][jn][2]);
                o.w = bf16b(acc[im][jn][3]);
                *(ushort4*)&C[(size_t)r * N + c] = o;
            } else {
                *(f32x4*)&C[(size_t)r * N + c] = acc[im][jn];
            }
        }
}

// ---------------------------------------------------------------------------
// Fused attention (R4/best config, unchanged).
// blockIdx.x < 32: banded+gather flash tile (S^T MFMA + register prefetch).
// blockIdx.x in [32, 32+2*NSPL): global rows, SPLIT-K flash-decoding
// (256 blocks @ NSPL=8, 2 iters each, partials to workspace; combine merges).
// ---------------------------------------------------------------------------
__global__ __launch_bounds__(256) void attn_fused(const unsigned short* __restrict__ qkv16,
                                                  unsigned short* __restrict__ aout16,
                                                  float* __restrict__ pO,
                                                  float* __restrict__ pM,
                                                  float* __restrict__ pL) {
    __shared__ __align__(16) unsigned char smem[38912];
    const int tid = threadIdx.x;
    const int h = blockIdx.y;
    const int w    = tid >> 6;
    const int lane = tid & 63;
    const int quad = lane >> 4;
    const int l15  = lane & 15;

    if (blockIdx.x < 32) {
        // ----------------- banded path (S^T MFMA + prefetch) -----------------
        ushort_t* Qs = (ushort_t*)smem;              // [64][72] bf16, 9216 B
        ushort_t* Ks = (ushort_t*)(smem + 9216);     // [64][72]
        ushort_t* Vt = (ushort_t*)(smem + 18432);    // [64][72]  Vt[d][key]
        ushort_t* Ps = (ushort_t*)(smem + 27648);    // [64][72]  Ps[q][key]

        const int bq = blockIdx.x;
        const int q0 = bq * 64;
        const int qi = q0 + w * 16 + l15;   // this lane's query

        for (int f = tid; f < 512; f += 256) {
            int row = f >> 3, c8 = f & 7;
            *(uint4*)&Qs[row * 72 + c8 * 8] =
                *(const uint4*)&qkv16[(size_t)(q0 + row) * (3 * HID) + h * HD + c8 * 8];
        }

        float mq = -1.0e30f, lq = 0.f;
        f32x4 Oacc[4];
        #pragma unroll
        for (int jt = 0; jt < 4; ++jt) Oacc[jt] = (f32x4){0.f, 0.f, 0.f, 0.f};

        const int t0 = max(bq - 2, 0);
        const int t1 = min(bq + 2, SEQ / 64 - 1);

        uint4 pk[2];
        uint2 pva[2], pvb[2];

        auto prefetch = [&](int tt2, bool g2) {
            const int nf = g2 ? 256 : 512;
            #pragma unroll
            for (int u = 0; u < 2; ++u) {
                const int f = tid + u * 256;
                if (f < nf) {
                    const int row = f >> 3, c8 = f & 7;
                    const size_t gb = (size_t)(g2 ? (row << 6) : (tt2 * 64 + row))
                                          * (3 * HID) + HID + h * HD + c8 * 8;
                    pk[u] = *(const uint4*)&qkv16[gb];
                    const int kp = f >> 4, dc = f & 15;
                    const int k0i = 2 * kp, k1i = 2 * kp + 1;
                    const size_t b0 = (size_t)(g2 ? (k0i << 6) : (tt2 * 64 + k0i))
                                          * (3 * HID) + 2 * HID + h * HD + dc * 4;
                    const size_t b1 = (size_t)(g2 ? (k1i << 6) : (tt2 * 64 + k1i))
                                          * (3 * HID) + 2 * HID + h * HD + dc * 4;
                    pva[u] = *(const uint2*)&qkv16[b0];
                    pvb[u] = *(const uint2*)&qkv16[b1];
                }
            }
        };
        auto commit = [&](bool g2) {
            const int nf = g2 ? 256 : 512;
            #pragma unroll
            for (int u = 0; u < 2; ++u) {
                const int f = tid + u * 256;
                if (f < nf) {
                    const int row = f >> 3, c8 = f & 7;
                    *(uint4*)&Ks[row * 72 + c8 * 8] = pk[u];
                    const int kp = f >> 4, dc = f & 15;
                    uint2 va = pva[u], vb = pvb[u];
                    unsigned int w0 = (va.x & 0xFFFFu) | (vb.x << 16);
                    unsigned int w1 = (va.x >> 16)     | (vb.x & 0xFFFF0000u);
                    unsigned int w2 = (va.y & 0xFFFFu) | (vb.y << 16);
                    unsigned int w3 = (va.y >> 16)     | (vb.y & 0xFFFF0000u);
                    *(unsigned int*)&Vt[(dc * 4 + 0) * 72 + 2 * kp] = w0;
                    *(unsigned int*)&Vt[(dc * 4 + 1) * 72 + 2 * kp] = w1;
                    *(unsigned int*)&Vt[(dc * 4 + 2) * 72 + 2 * kp] = w2;
                    *(unsigned int*)&Vt[(dc * 4 + 3) * 72 + 2 * kp] = w3;
                }
            }
        };

        prefetch(t0, false);
        commit(false);
        __syncthreads();

        for (int tt = t0; tt <= t1 + 1; ++tt) {
            const bool gather = (tt == t1 + 1);
            const bool hasnext = (tt < t1 + 1);
            if (hasnext) prefetch(tt + 1, (tt + 1) == t1 + 1);

            short8 bQ0 = *(const short8*)&Qs[(w * 16 + l15) * 72 + quad * 8];
            short8 bQ1 = *(const short8*)&Qs[(w * 16 + l15) * 72 + 32 + quad * 8];
            f32x4 st[4];
            #pragma unroll
            for (int kt = 0; kt < 4; ++kt) {
                short8 aK0 = *(const short8*)&Ks[(kt * 16 + l15) * 72 + quad * 8];
                short8 aK1 = *(const short8*)&Ks[(kt * 16 + l15) * 72 + 32 + quad * 8];
                f32x4 z = (f32x4){0.f, 0.f, 0.f, 0.f};
                z = __builtin_amdgcn_mfma_f32_16x16x32_bf16(aK0, bQ0, z, 0, 0, 0);
                z = __builtin_amdgcn_mfma_f32_16x16x32_bf16(aK1, bQ1, z, 0, 0, 0);
                st[kt] = z;
            }

            float sv[4][4];
            float tm = -1.0e30f;
            #pragma unroll
            for (int kt = 0; kt < 4; ++kt)
                #pragma unroll
                for (int reg = 0; reg < 4; ++reg) {
                    const int c = kt * 16 + quad * 4 + reg;
                    const int j = gather ? (c << 6) : (tt * 64 + c);
                    const bool valid = gather ? ((c < 32) && (abs(qi - j) > WIN))
                                              : (abs(qi - j) <= WIN);
                    sv[kt][reg] = valid ? st[kt][reg] * 0.125f : -1.0e30f;
                    tm = fmaxf(tm, sv[kt][reg]);
                }

            tm = fmaxf(tm, __shfl_xor(tm, 16));
            tm = fmaxf(tm, __shfl_xor(tm, 32));
            const float mn = fmaxf(mq, tm);
            const float alpha = __expf(mq - mn);
            float p[4][4];
            float ts = 0.f;
            #pragma unroll
            for (int kt = 0; kt < 4; ++kt)
                #pragma unroll
                for (int reg = 0; reg < 4; ++reg) {
                    p[kt][reg] = __expf(sv[kt][reg] - mn);
                    ts += p[kt][reg];
                }
            ts += __shfl_xor(ts, 16);
            ts += __shfl_xor(ts, 32);
            lq = lq * alpha + ts;
            mq = mn;

            #pragma unroll
            for (int kt = 0; kt < 4; ++kt) {
                ushort4 pkt;
                pkt.x = bf16b(p[kt][0]); pkt.y = bf16b(p[kt][1]);
                pkt.z = bf16b(p[kt][2]); pkt.w = bf16b(p[kt][3]);
                *(ushort4*)&Ps[(w * 16 + l15) * 72 + kt * 16 + quad * 4] = pkt;
            }
            #pragma unroll
            for (int jt = 0; jt < 4; ++jt) {
                Oacc[jt][0] *= alpha; Oacc[jt][1] *= alpha;
                Oacc[jt][2] *= alpha; Oacc[jt][3] *= alpha;
            }

            short8 bP0 = *(const short8*)&Ps[(w * 16 + l15) * 72 + quad * 8];
            short8 bP1 = *(const short8*)&Ps[(w * 16 + l15) * 72 + 32 + quad * 8];
            #pragma unroll
            for (int jt = 0; jt < 4; ++jt) {
                short8 aV0 = *(const short8*)&Vt[(jt * 16 + l15) * 72 + quad * 8];
                short8 aV1 = *(const short8*)&Vt[(jt * 16 + l15) * 72 + 32 + quad * 8];
                Oacc[jt] = __builtin_amdgcn_mfma_f32_16x16x32_bf16(aV0, bP0, Oacc[jt], 0, 0, 0);
                Oacc[jt] = __builtin_amdgcn_mfma_f32_16x16x32_bf16(aV1, bP1, Oacc[jt], 0, 0, 0);
            }

            if (hasnext) {
                __syncthreads();
                commit((tt + 1) == t1 + 1);
                __syncthreads();
            }
        }

        if (!(w == 0 && l15 == 0)) {   // skip global rows (qi % 64 == 0)
            const float inv = 1.0f / lq;
            #pragma unroll
            for (int jt = 0; jt < 4; ++jt) {
                ushort4 o;
                o.x = bf16b(Oacc[jt][0] * inv);
                o.y = bf16b(Oacc[jt][1] * inv);
                o.z = bf16b(Oacc[jt][2] * inv);
                o.w = bf16b(Oacc[jt][3] * inv);
                *(ushort4*)&aout16[(size_t)qi * HID + h * HD + jt * 16 + quad * 4] = o;
            }
        }
    } else {
        // ------------- global-row path: SPLIT-K MFMA flash-decoding ---------
        constexpr int KPS = SEQ / NSPL;        // keys per split (256 @ NSPL=8)
        const int sid = blockIdx.x - 32;       // 0 .. 2*NSPL-1
        const int gh  = sid / NSPL;            // 0 or 1 (16 q-rows each)
        const int sp  = sid % NSPL;            // key split
        ushort_t* Ksw = (ushort_t*)(smem + w * 9728);
        ushort_t* Vtw = (ushort_t*)(smem + w * 9728 + 4608);
        ushort_t* Psw = (ushort_t*)(smem + w * 9728 + 8704);

        const size_t qrow = (size_t)((gh * 16 + l15) * 64) * (3 * HID) + h * HD;
        short8 bQ0 = *(const short8*)&qkv16[qrow + quad * 8];
        short8 bQ1 = *(const short8*)&qkv16[qrow + 32 + quad * 8];

        float mq = -1.0e30f, lq = 0.f;
        f32x4 Oacc[4];
        #pragma unroll
        for (int jt = 0; jt < 4; ++jt) Oacc[jt] = (f32x4){0.f, 0.f, 0.f, 0.f};

        #pragma unroll
        for (int s = 0; s < KPS / 128; ++s) {
            const int kb = sp * KPS + w * (KPS / 4) + s * 32;
            #pragma unroll
            for (int u = 0; u < 4; ++u) {
                const int unit = lane + u * 64;
                const int row = unit >> 3, c8 = unit & 7;
                *(uint4*)&Ksw[row * 72 + c8 * 8] =
                    *(const uint4*)&qkv16[(size_t)(kb + row) * (3 * HID) + HID + h * HD + c8 * 8];
            }
            #pragma unroll
            for (int u = 0; u < 4; ++u) {
                const int unit = lane + u * 64;
                const int kp = unit >> 4, dc = unit & 15;
                const size_t b0 = (size_t)(kb + 2 * kp) * (3 * HID) + 2 * HID + h * HD + dc * 4;
                uint2 va = *(const uint2*)&qkv16[b0];
                uint2 vb = *(const uint2*)&qkv16[b0 + 3 * HID];
                unsigned int w0 = (va.x & 0xFFFFu) | (vb.x << 16);
                unsigned int w1 = (va.x >> 16)     | (vb.x & 0xFFFF0000u);
                unsigned int w2 = (va.y & 0xFFFFu) | (vb.y << 16);
                unsigned int w3 = (va.y >> 16)     | (vb.y & 0xFFFF0000u);
                *(unsigned int*)&Vtw[(dc * 4 + 0) * 32 + 2 * kp] = w0;
                *(unsigned int*)&Vtw[(dc * 4 + 1) * 32 + 2 * kp] = w1;
                *(unsigned int*)&Vtw[(dc * 4 + 2) * 32 + 2 * kp] = w2;
                *(unsigned int*)&Vtw[(dc * 4 + 3) * 32 + 2 * kp] = w3;
            }

            f32x4 st[2];
            #pragma unroll
            for (int kt = 0; kt < 2; ++kt) {
                short8 aK0 = *(const short8*)&Ksw[(kt * 16 + l15) * 72 + quad * 8];
                short8 aK1 = *(const short8*)&Ksw[(kt * 16 + l15) * 72 + 32 + quad * 8];
                f32x4 z = (f32x4){0.f, 0.f, 0.f, 0.f};
                z = __builtin_amdgcn_mfma_f32_16x16x32_bf16(aK0, bQ0, z, 0, 0, 0);
                z = __builtin_amdgcn_mfma_f32_16x16x32_bf16(aK1, bQ1, z, 0, 0, 0);
                st[kt] = z;
            }

            float sv[2][4];
            float tm = -1.0e30f;
            #pragma unroll
            for (int kt = 0; kt < 2; ++kt)
                #pragma unroll
                for (int reg = 0; reg < 4; ++reg) {
                    sv[kt][reg] = st[kt][reg] * 0.125f;
                    tm = fmaxf(tm, sv[kt][reg]);
                }
            tm = fmaxf(tm, __shfl_xor(tm, 16));
            tm = fmaxf(tm, __shfl_xor(tm, 32));
            const float mn = fmaxf(mq, tm);
            const float alpha = __expf(mq - mn);
            float p[2][4];
            float ts = 0.f;
            #pragma unroll
            for (int kt = 0; kt < 2; ++kt)
                #pragma unroll
                for (int reg = 0; reg < 4; ++reg) {
                    p[kt][reg] = __expf(sv[kt][reg] - mn);
                    ts += p[kt][reg];
                }
            ts += __shfl_xor(ts, 16);
            ts += __shfl_xor(ts, 32);
            lq = lq * alpha + ts;
            mq = mn;

            #pragma unroll
            for (int kt = 0; kt < 2; ++kt) {
                ushort4 pkt;
                pkt.x = bf16b(p[kt][0]); pkt.y = bf16b(p[kt][1]);
                pkt.z = bf16b(p[kt][2]); pkt.w = bf16b(p[kt][3]);
                *(ushort4*)&Psw[l15 * 32 + kt * 16 + quad * 4] = pkt;
            }
            #pragma unroll
            for (int jt = 0; jt < 4; ++jt) {
                Oacc[jt][0] *= alpha; Oacc[jt][1] *= alpha;
                Oacc[jt][2] *= alpha; Oacc[jt][3] *= alpha;
            }

            short8 bP = *(const short8*)&Psw[l15 * 32 + quad * 8];
            #pragma unroll
            for (int jt = 0; jt < 4; ++jt) {
                short8 aV = *(const short8*)&Vtw[(jt * 16 + l15) * 32 + quad * 8];
                Oacc[jt] = __builtin_amdgcn_mfma_f32_16x16x32_bf16(aV, bP, Oacc[jt], 0, 0, 0);
            }
        }

        // cross-wave combine -> per-split partial (m, l, unnormalized O)
        __syncthreads();
        float* Om = (float*)smem;              // [4][16][64]
        float* Ml = (float*)(smem + 16384);    // [4][16]
        float* Ll = (float*)(smem + 16640);    // [4][16]
        #pragma unroll
        for (int jt = 0; jt < 4; ++jt)
            #pragma unroll
            for (int reg = 0; reg < 4; ++reg)
                Om[(w * 16 + l15) * 64 + jt * 16 + quad * 4 + reg] = Oacc[jt][reg];
        if (quad == 0) { Ml[w * 16 + l15] = mq; Ll[w * 16 + l15] = lq; }
        __syncthreads();

        const int pt = (h * 2 + gh) * NSPL + sp;   // partial-tile index
        const int d = tid & 63;
        #pragma unroll
        for (int k = 0; k < 4; ++k) {
            const int q = (tid >> 6) * 4 + k;
            float m0 = Ml[q], m1 = Ml[16 + q], m2 = Ml[32 + q], m3 = Ml[48 + q];
            float mM = fmaxf(fmaxf(m0, m1), fmaxf(m2, m3));
            float e0 = __expf(m0 - mM), e1 = __expf(m1 - mM);
            float e2 = __expf(m2 - mM), e3 = __expf(m3 - mM);
            float l = e0 * Ll[q] + e1 * Ll[16 + q] + e2 * Ll[32 + q] + e3 * Ll[48 + q];
            float o = e0 * Om[(q) * 64 + d]        + e1 * Om[(16 + q) * 64 + d]
                    + e2 * Om[(32 + q) * 64 + d]   + e3 * Om[(48 + q) * 64 + d];
            pO[(size_t)pt * 1024 + q * 64 + d] = o;
            if (d == 0) { pM[pt * 16 + q] = mM; pL[pt * 16 + q] = l; }
        }
    }
}

// ---------------------------------------------------------------------------
// Merge NSPL per-split partials into aout16 for the 32 global rows.
// 32 blocks x 256 threads; each block = one (head, gh) pair.
// ---------------------------------------------------------------------------
__global__ __launch_bounds__(256) void attn_combine(const float* __restrict__ pO,
                                                    const float* __restrict__ pM,
                                                    const float* __restrict__ pL,
                                                    unsigned short* __restrict__ aout16) {
    const int bid = blockIdx.x;         // 0..31
    const int h = bid >> 1, gh = bid & 1;
    const int base = (h * 2 + gh) * NSPL;
    #pragma unroll
    for (int k = 0; k < 4; ++k) {
        const int idx = threadIdx.x + k * 256;   // 0..1023
        const int q = idx >> 6, d = idx & 63;
        float mM = -1.0e30f;
        #pragma unroll
        for (int sp = 0; sp < NSPL; ++sp)
            mM = fmaxf(mM, pM[(base + sp) * 16 + q]);
        float l = 0.f, o = 0.f;
        #pragma unroll
        for (int sp = 0; sp < NSPL; ++sp) {
            const float e = __expf(pM[(base + sp) * 16 + q] - mM);
            l += e * pL[(base + sp) * 16 + q];
            o += e * pO[(size_t)(base + sp) * 1024 + q * 64 + d];
        }
        const int row = (gh * 16 + q) * 64;      // global token index
        aout16[(size_t)row * HID + h * HD + d] = bf16b(o / l);
    }
}

extern "C" void kernel_launch(void* const* d_in, const int* in_sizes, int n_in,
                              void* d_out, int out_size, void* d_ws, size_t ws_size,
                              hipStream_t stream) {
    const float* x    = (const float*)d_in[0];   // [2048,1024] fp32
    const float* Wqkv = (const float*)d_in[1];   // [3072,1024] fp32
    const float* Wout = (const float*)d_in[2];   // [1024,1024] fp32
    float* out = (float*)d_out;                  // [2048,1024] fp32

    unsigned short* x16    = (unsigned short*)d_ws;                 // 2048*1024
    unsigned short* wq16   = x16  + (size_t)SEQ * HID;              // 3072*1024
    unsigned short* wo16   = wq16 + (size_t)3 * HID * HID;          // 1024*1024
    unsigned short* qkv16  = wo16 + (size_t)HID * HID;              // 2048*3072
    unsigned short* aout16 = qkv16 + (size_t)SEQ * 3 * HID;         // 2048*1024
    float* pO = (float*)(aout16 + (size_t)SEQ * HID);               // 2*NH*NSPL*1024 f32
    float* pM = pO + (size_t)NH * 2 * NSPL * 1024;                  // 2*NH*NSPL*16 f32
    float* pL = pM + (size_t)NH * 2 * NSPL * 16;                    // 2*NH*NSPL*16 f32

    // 0) fp32 -> bf16 conversions
    cvt_bf16<<<dim3(1024), 256, 0, stream>>>(
        (const float4*)x, (const float4*)Wqkv, (const float4*)Wout,
        (ushort4*)x16, (ushort4*)wq16, (ushort4*)wo16);

    // 1) qkv16 = x16 @ wq16^T (bf16 out): 64x128 tile, BK=128, NW=8
    //    (512 threads) -> 768 blocks, 48KB LDS, 24 waves/CU (R9: -1.2us)
    gemm_bt16<64, 128, 128, 8, unsigned short><<<dim3(3 * HID / 128, SEQ / 64), 512, 0, stream>>>(
        x16, wq16, qkv16, SEQ, 3 * HID, HID);

    // 2) fused banded + split-K global attention, then split merge
    attn_fused<<<dim3(32 + 2 * NSPL, NH), 256, 0, stream>>>(
        qkv16, aout16, pO, pM, pL);
    attn_combine<<<dim3(32), 256, 0, stream>>>(pO, pM, pL, aout16);

    // 3) out = aout16 @ wo16^T (fp32 out): 64x64 tile, BK=128, NW=8
    //    (512 threads) -> 512 blocks, 16 waves/CU (R10: was 8 = 2/SIMD floor)
    gemm_bt16<64, 64, 128, 8, float><<<dim3(HID / 64, SEQ / 64), 512, 0, stream>>>(
        aout16, wo16, out, SEQ, HID, HID);
}

// Round 11
// 136.572 us; speedup vs baseline: 1.0142x; 1.0142x over previous
//
#include <hip/hip_runtime.h>
#include <hip/hip_bf16.h>
#include <math.h>

// Problem constants (B=1)
#define SEQ   2048
#define HID   1024
#define NH    16
#define HD    64
#define WIN   128
#define GSTR  64
#define NSPL  8     // key-range splits (8 best: 16 regressed +6.5us, R7)

typedef __attribute__((ext_vector_type(8))) short short8;   // 8 bf16 = 4 VGPRs
typedef __attribute__((ext_vector_type(4))) float f32x4;    // MFMA C/D
typedef unsigned short ushort_t;

// RNE fp32 -> bf16 bits (finite inputs)
__device__ inline unsigned short bf16b(float f) {
    union { float f; unsigned int u; } v; v.f = f;
    return (unsigned short)((v.u + 0x7FFFu + ((v.u >> 16) & 1u)) >> 16);
}

#define GLOAD_LDS16(gp, lp)                                                    \
    __builtin_amdgcn_global_load_lds(                                          \
        (const __attribute__((address_space(1))) unsigned int*)(gp),           \
        (__attribute__((address_space(3))) unsigned int*)(lp), 16, 0, 0)

// ---------------------------------------------------------------------------
// fp32 -> bf16 pre-convert of x, Wqkv, Wout
// ---------------------------------------------------------------------------
__global__ __launch_bounds__(256) void cvt_bf16(const float4* __restrict__ x,
                                                const float4* __restrict__ wq,
                                                const float4* __restrict__ wo,
                                                ushort4* __restrict__ x16,
                                                ushort4* __restrict__ wq16,
                                                ushort4* __restrict__ wo16) {
    for (int idx = blockIdx.x * 256 + threadIdx.x; idx < 1572864;
         idx += gridDim.x * 256) {
        const float4* src; ushort4* dst; int off;
        if (idx < 524288)       { src = x;  dst = x16;  off = idx; }
        else if (idx < 1310720) { src = wq; dst = wq16; off = idx - 524288; }
        else                    { src = wo; dst = wo16; off = idx - 1310720; }
        float4 v = src[off];
        ushort4 o;
        o.x = bf16b(v.x); o.y = bf16b(v.y); o.z = bf16b(v.z); o.w = bf16b(v.w);
        dst[off] = o;
    }
}

// ---------------------------------------------------------------------------
// MFMA GEMM: C[M,N] = A[M,K] @ B[N,K]^T, bf16 in, fp32 acc.
// BK=128, 2-barrier/K-step (best-measured schedule; pipelining/tile variants
// all null or worse — R3-R8 ledger).
// R9: QKV NW=8 (24 waves/CU) -1.2us (keep). R10: out-GEMM NW=8 REGRESSED
// +1.8us (per-wave frag grid fell to 2x1, halving MFMA density) -> NW=4.
// R11: XCD chunk swizzle — consecutive dispatch ids share an A-panel but
// round-robin across 8 XCD L2s; chunking gives each XCD 4 contiguous y-rows
// so A-panels stay in the local L2 (T1; bijective since nwg%8==0).
// R6 lesson: NO device-scope fences in hot kernels (+43us on 8 XCDs).
// ---------------------------------------------------------------------------
template <int BM, int BN, int BK, int NW, typename OT>
__global__ __launch_bounds__(NW * 64) void gemm_bt16(const unsigned short* __restrict__ A,
                                                     const unsigned short* __restrict__ B,
                                                     OT* __restrict__ C,
                                                     int M, int N, int K) {
    constexpr int WMW = 2;                 // waves along M
    constexpr int WNW = NW / 2;            // waves along N
    constexpr int MI = (BM / WMW) / 16;    // 16-row frags per wave
    constexpr int NJ = (BN / WNW) / 16;    // 16-col frags per wave
    constexpr int NP = BK / 32;            // 32-col panels per K-step
    __shared__ unsigned short As[NP][BM * 32];
    __shared__ unsigned short Bs[NP][BN * 32];

    const int tid  = threadIdx.x;
    const int wave = tid >> 6;
    const int lane = tid & 63;
    const int quad = lane >> 4;
    const int l15  = lane & 15;

    // R11: XCD chunk swizzle (hardware dispatch order is x-major; XCD = id%8)
    const int gx  = gridDim.x;
    const int nwg = gx * gridDim.y;
    int bid = blockIdx.y * gx + blockIdx.x;
    bid = (bid & 7) * (nwg >> 3) + (bid >> 3);   // bijective: nwg % 8 == 0
    const int bm = (bid / gx) * BM;
    const int bn = (bid % gx) * BN;

    const int wm = (wave % WMW) * (BM / WMW);
    const int wn = (wave / WMW) * (BN / WNW);
    const int srow = lane >> 2;
    const int scol = (lane & 3) * 8;

    f32x4 acc[MI][NJ];
    #pragma unroll
    for (int i = 0; i < MI; ++i)
        #pragma unroll
        for (int j = 0; j < NJ; ++j)
            acc[i][j] = (f32x4){0.f, 0.f, 0.f, 0.f};

    for (int k0 = 0; k0 < K; k0 += BK) {
        // stage: flat unit loop; unit = (panel hh, 16-row group rg)
        #pragma unroll
        for (int u = wave; u < NP * (BM / 16); u += NW) {
            const int hh = u / (BM / 16);
            const int rg = u % (BM / 16);
            const int row = rg * 16 + srow;
            GLOAD_LDS16(A + (size_t)(bm + row) * K + k0 + hh * 32 + scol,
                        &As[hh][(size_t)row * 32 + scol]);
        }
        #pragma unroll
        for (int u = wave; u < NP * (BN / 16); u += NW) {
            const int hh = u / (BN / 16);
            const int rg = u % (BN / 16);
            const int row = rg * 16 + srow;
            GLOAD_LDS16(B + (size_t)(bn + row) * K + k0 + hh * 32 + scol,
                        &Bs[hh][(size_t)row * 32 + scol]);
        }
        __syncthreads();

        #pragma unroll
        for (int hh = 0; hh < NP; ++hh) {
            short8 a[MI], b[NJ];
            #pragma unroll
            for (int im = 0; im < MI; ++im)
                a[im] = *(const short8*)&As[hh][(wm + im * 16 + l15) * 32 + quad * 8];
            #pragma unroll
            for (int jn = 0; jn < NJ; ++jn)
                b[jn] = *(const short8*)&Bs[hh][(wn + jn * 16 + l15) * 32 + quad * 8];

            #pragma unroll
            for (int im = 0; im < MI; ++im)
                #pragma unroll
                for (int jn = 0; jn < NJ; ++jn)
                    acc[im][jn] = __builtin_amdgcn_mfma_f32_16x16x32_bf16(
                        b[jn], a[im], acc[im][jn], 0, 0, 0);
        }
        __syncthreads();
    }

    // Epilogue: lane holds C[r = ...+l15][c = ...+quad*4 + (0..3)] -> vector store
    #pragma unroll
    for (int im = 0; im < MI; ++im)
        #pragma unroll
        for (int jn = 0; jn < NJ; ++jn) {
            const int r = bm + wm + im * 16 + l15;
            const int c = bn + wn + jn * 16 + quad * 4;
            if constexpr (sizeof(OT) == 2) {
                ushort4 o;
                o.x = bf16b(acc[im][jn][0]);
                o.y = bf16b(acc[im][jn][1]);
                o.z = bf16b(acc[im][jn][2]);
                o.w = bf16b(acc[im][jn][3]);
                *(ushort4*)&C[(size_t)r * N + c] = o;
            } else {
                *(f32x4*)&C[(size_t)r * N + c] = acc[im][jn];
            }
        }
}

// ---------------------------------------------------------------------------
// Fused attention (R4/best config, unchanged).
// blockIdx.x < 32: banded+gather flash tile (S^T MFMA + register prefetch).
// blockIdx.x in [32, 32+2*NSPL): global rows, SPLIT-K flash-decoding
// (256 blocks @ NSPL=8, 2 iters each, partials to workspace; combine merges).
// ---------------------------------------------------------------------------
__global__ __launch_bounds__(256) void attn_fused(const unsigned short* __restrict__ qkv16,
                                                  unsigned short* __restrict__ aout16,
                                                  float* __restrict__ pO,
                                                  float* __restrict__ pM,
                                                  float* __restrict__ pL) {
    __shared__ __align__(16) unsigned char smem[38912];
    const int tid = threadIdx.x;
    const int h = blockIdx.y;
    const int w    = tid >> 6;
    const int lane = tid & 63;
    const int quad = lane >> 4;
    const int l15  = lane & 15;

    if (blockIdx.x < 32) {
        // ----------------- banded path (S^T MFMA + prefetch) -----------------
        ushort_t* Qs = (ushort_t*)smem;              // [64][72] bf16, 9216 B
        ushort_t* Ks = (ushort_t*)(smem + 9216);     // [64][72]
        ushort_t* Vt = (ushort_t*)(smem + 18432);    // [64][72]  Vt[d][key]
        ushort_t* Ps = (ushort_t*)(smem + 27648);    // [64][72]  Ps[q][key]

        const int bq = blockIdx.x;
        const int q0 = bq * 64;
        const int qi = q0 + w * 16 + l15;   // this lane's query

        for (int f = tid; f < 512; f += 256) {
            int row = f >> 3, c8 = f & 7;
            *(uint4*)&Qs[row * 72 + c8 * 8] =
                *(const uint4*)&qkv16[(size_t)(q0 + row) * (3 * HID) + h * HD + c8 * 8];
        }

        float mq = -1.0e30f, lq = 0.f;
        f32x4 Oacc[4];
        #pragma unroll
        for (int jt = 0; jt < 4; ++jt) Oacc[jt] = (f32x4){0.f, 0.f, 0.f, 0.f};

        const int t0 = max(bq - 2, 0);
        const int t1 = min(bq + 2, SEQ / 64 - 1);

        uint4 pk[2];
        uint2 pva[2], pvb[2];

        auto prefetch = [&](int tt2, bool g2) {
            const int nf = g2 ? 256 : 512;
            #pragma unroll
            for (int u = 0; u < 2; ++u) {
                const int f = tid + u * 256;
                if (f < nf) {
                    const int row = f >> 3, c8 = f & 7;
                    const size_t gb = (size_t)(g2 ? (row << 6) : (tt2 * 64 + row))
                                          * (3 * HID) + HID + h * HD + c8 * 8;
                    pk[u] = *(const uint4*)&qkv16[gb];
                    const int kp = f >> 4, dc = f & 15;
                    const int k0i = 2 * kp, k1i = 2 * kp + 1;
                    const size_t b0 = (size_t)(g2 ? (k0i << 6) : (tt2 * 64 + k0i))
                                          * (3 * HID) + 2 * HID + h * HD + dc * 4;
                    const size_t b1 = (size_t)(g2 ? (k1i << 6) : (tt2 * 64 + k1i))
                                          * (3 * HID) + 2 * HID + h * HD + dc * 4;
                    pva[u] = *(const uint2*)&qkv16[b0];
                    pvb[u] = *(const uint2*)&qkv16[b1];
                }
            }
        };
        auto commit = [&](bool g2) {
            const int nf = g2 ? 256 : 512;
            #pragma unroll
            for (int u = 0; u < 2; ++u) {
                const int f = tid + u * 256;
                if (f < nf) {
                    const int row = f >> 3, c8 = f & 7;
                    *(uint4*)&Ks[row * 72 + c8 * 8] = pk[u];
                    const int kp = f >> 4, dc = f & 15;
                    uint2 va = pva[u], vb = pvb[u];
                    unsigned int w0 = (va.x & 0xFFFFu) | (vb.x << 16);
                    unsigned int w1 = (va.x >> 16)     | (vb.x & 0xFFFF0000u);
                    unsigned int w2 = (va.y & 0xFFFFu) | (vb.y << 16);
                    unsigned int w3 = (va.y >> 16)     | (vb.y & 0xFFFF0000u);
                    *(unsigned int*)&Vt[(dc * 4 + 0) * 72 + 2 * kp] = w0;
                    *(unsigned int*)&Vt[(dc * 4 + 1) * 72 + 2 * kp] = w1;
                    *(unsigned int*)&Vt[(dc * 4 + 2) * 72 + 2 * kp] = w2;
                    *(unsigned int*)&Vt[(dc * 4 + 3) * 72 + 2 * kp] = w3;
                }
            }
        };

        prefetch(t0, false);
        commit(false);
        __syncthreads();

        for (int tt = t0; tt <= t1 + 1; ++tt) {
            const bool gather = (tt == t1 + 1);
            const bool hasnext = (tt < t1 + 1);
            if (hasnext) prefetch(tt + 1, (tt + 1) == t1 + 1);

            short8 bQ0 = *(const short8*)&Qs[(w * 16 + l15) * 72 + quad * 8];
            short8 bQ1 = *(const short8*)&Qs[(w * 16 + l15) * 72 + 32 + quad * 8];
            f32x4 st[4];
            #pragma unroll
            for (int kt = 0; kt < 4; ++kt) {
                short8 aK0 = *(const short8*)&Ks[(kt * 16 + l15) * 72 + quad * 8];
                short8 aK1 = *(const short8*)&Ks[(kt * 16 + l15) * 72 + 32 + quad * 8];
                f32x4 z = (f32x4){0.f, 0.f, 0.f, 0.f};
                z = __builtin_amdgcn_mfma_f32_16x16x32_bf16(aK0, bQ0, z, 0, 0, 0);
                z = __builtin_amdgcn_mfma_f32_16x16x32_bf16(aK1, bQ1, z, 0, 0, 0);
                st[kt] = z;
            }

            float sv[4][4];
            float tm = -1.0e30f;
            #pragma unroll
            for (int kt = 0; kt < 4; ++kt)
                #pragma unroll
                for (int reg = 0; reg < 4; ++reg) {
                    const int c = kt * 16 + quad * 4 + reg;
                    const int j = gather ? (c << 6) : (tt * 64 + c);
                    const bool valid = gather ? ((c < 32) && (abs(qi - j) > WIN))
                                              : (abs(qi - j) <= WIN);
                    sv[kt][reg] = valid ? st[kt][reg] * 0.125f : -1.0e30f;
                    tm = fmaxf(tm, sv[kt][reg]);
                }

            tm = fmaxf(tm, __shfl_xor(tm, 16));
            tm = fmaxf(tm, __shfl_xor(tm, 32));
            const float mn = fmaxf(mq, tm);
            const float alpha = __expf(mq - mn);
            float p[4][4];
            float ts = 0.f;
            #pragma unroll
            for (int kt = 0; kt < 4; ++kt)
                #pragma unroll
                for (int reg = 0; reg < 4; ++reg) {
                    p[kt][reg] = __expf(sv[kt][reg] - mn);
                    ts += p[kt][reg];
                }
            ts += __shfl_xor(ts, 16);
            ts += __shfl_xor(ts, 32);
            lq = lq * alpha + ts;
            mq = mn;

            #pragma unroll
            for (int kt = 0; kt < 4; ++kt) {
                ushort4 pkt;
                pkt.x = bf16b(p[kt][0]); pkt.y = bf16b(p[kt][1]);
                pkt.z = bf16b(p[kt][2]); pkt.w = bf16b(p[kt][3]);
                *(ushort4*)&Ps[(w * 16 + l15) * 72 + kt * 16 + quad * 4] = pkt;
            }
            #pragma unroll
            for (int jt = 0; jt < 4; ++jt) {
                Oacc[jt][0] *= alpha; Oacc[jt][1] *= alpha;
                Oacc[jt][2] *= alpha; Oacc[jt][3] *= alpha;
            }

            short8 bP0 = *(const short8*)&Ps[(w * 16 + l15) * 72 + quad * 8];
            short8 bP1 = *(const short8*)&Ps[(w * 16 + l15) * 72 + 32 + quad * 8];
            #pragma unroll
            for (int jt = 0; jt < 4; ++jt) {
                short8 aV0 = *(const short8*)&Vt[(jt * 16 + l15) * 72 + quad * 8];
                short8 aV1 = *(const short8*)&Vt[(jt * 16 + l15) * 72 + 32 + quad * 8];
                Oacc[jt] = __builtin_amdgcn_mfma_f32_16x16x32_bf16(aV0, bP0, Oacc[jt], 0, 0, 0);
                Oacc[jt] = __builtin_amdgcn_mfma_f32_16x16x32_bf16(aV1, bP1, Oacc[jt], 0, 0, 0);
            }

            if (hasnext) {
                __syncthreads();
                commit((tt + 1) == t1 + 1);
                __syncthreads();
            }
        }

        if (!(w == 0 && l15 == 0)) {   // skip global rows (qi % 64 == 0)
            const float inv = 1.0f / lq;
            #pragma unroll
            for (int jt = 0; jt < 4; ++jt) {
                ushort4 o;
                o.x = bf16b(Oacc[jt][0] * inv);
                o.y = bf16b(Oacc[jt][1] * inv);
                o.z = bf16b(Oacc[jt][2] * inv);
                o.w = bf16b(Oacc[jt][3] * inv);
                *(ushort4*)&aout16[(size_t)qi * HID + h * HD + jt * 16 + quad * 4] = o;
            }
        }
    } else {
        // ------------- global-row path: SPLIT-K MFMA flash-decoding ---------
        constexpr int KPS = SEQ / NSPL;        // keys per split (256 @ NSPL=8)
        const int sid = blockIdx.x - 32;       // 0 .. 2*NSPL-1
        const int gh  = sid / NSPL;            // 0 or 1 (16 q-rows each)
        const int sp  = sid % NSPL;            // key split
        ushort_t* Ksw = (ushort_t*)(smem + w * 9728);
        ushort_t* Vtw = (ushort_t*)(smem + w * 9728 + 4608);
        ushort_t* Psw = (ushort_t*)(smem + w * 9728 + 8704);

        const size_t qrow = (size_t)((gh * 16 + l15) * 64) * (3 * HID) + h * HD;
        short8 bQ0 = *(const short8*)&qkv16[qrow + quad * 8];
        short8 bQ1 = *(const short8*)&qkv16[qrow + 32 + quad * 8];

        float mq = -1.0e30f, lq = 0.f;
        f32x4 Oacc[4];
        #pragma unroll
        for (int jt = 0; jt < 4; ++jt) Oacc[jt] = (f32x4){0.f, 0.f, 0.f, 0.f};

        #pragma unroll
        for (int s = 0; s < KPS / 128; ++s) {
            const int kb = sp * KPS + w * (KPS / 4) + s * 32;
            #pragma unroll
            for (int u = 0; u < 4; ++u) {
                const int unit = lane + u * 64;
                const int row = unit >> 3, c8 = unit & 7;
                *(uint4*)&Ksw[row * 72 + c8 * 8] =
                    *(const uint4*)&qkv16[(size_t)(kb + row) * (3 * HID) + HID + h * HD + c8 * 8];
            }
            #pragma unroll
            for (int u = 0; u < 4; ++u) {
                const int unit = lane + u * 64;
                const int kp = unit >> 4, dc = unit & 15;
                const size_t b0 = (size_t)(kb + 2 * kp) * (3 * HID) + 2 * HID + h * HD + dc * 4;
                uint2 va = *(const uint2*)&qkv16[b0];
                uint2 vb = *(const uint2*)&qkv16[b0 + 3 * HID];
                unsigned int w0 = (va.x & 0xFFFFu) | (vb.x << 16);
                unsigned int w1 = (va.x >> 16)     | (vb.x & 0xFFFF0000u);
                unsigned int w2 = (va.y & 0xFFFFu) | (vb.y << 16);
                unsigned int w3 = (va.y >> 16)     | (vb.y & 0xFFFF0000u);
                *(unsigned int*)&Vtw[(dc * 4 + 0) * 32 + 2 * kp] = w0;
                *(unsigned int*)&Vtw[(dc * 4 + 1) * 32 + 2 * kp] = w1;
                *(unsigned int*)&Vtw[(dc * 4 + 2) * 32 + 2 * kp] = w2;
                *(unsigned int*)&Vtw[(dc * 4 + 3) * 32 + 2 * kp] = w3;
            }

            f32x4 st[2];
            #pragma unroll
            for (int kt = 0; kt < 2; ++kt) {
                short8 aK0 = *(const short8*)&Ksw[(kt * 16 + l15) * 72 + quad * 8];
                short8 aK1 = *(const short8*)&Ksw[(kt * 16 + l15) * 72 + 32 + quad * 8];
                f32x4 z = (f32x4){0.f, 0.f, 0.f, 0.f};
                z = __builtin_amdgcn_mfma_f32_16x16x32_bf16(aK0, bQ0, z, 0, 0, 0);
                z = __builtin_amdgcn_mfma_f32_16x16x32_bf16(aK1, bQ1, z, 0, 0, 0);
                st[kt] = z;
            }

            float sv[2][4];
            float tm = -1.0e30f;
            #pragma unroll
            for (int kt = 0; kt < 2; ++kt)
                #pragma unroll
                for (int reg = 0; reg < 4; ++reg) {
                    sv[kt][reg] = st[kt][reg] * 0.125f;
                    tm = fmaxf(tm, sv[kt][reg]);
                }
            tm = fmaxf(tm, __shfl_xor(tm, 16));
            tm = fmaxf(tm, __shfl_xor(tm, 32));
            const float mn = fmaxf(mq, tm);
            const float alpha = __expf(mq - mn);
            float p[2][4];
            float ts = 0.f;
            #pragma unroll
            for (int kt = 0; kt < 2; ++kt)
                #pragma unroll
                for (int reg = 0; reg < 4; ++reg) {
                    p[kt][reg] = __expf(sv[kt][reg] - mn);
                    ts += p[kt][reg];
                }
            ts += __shfl_xor(ts, 16);
            ts += __shfl_xor(ts, 32);
            lq = lq * alpha + ts;
            mq = mn;

            #pragma unroll
            for (int kt = 0; kt < 2; ++kt) {
                ushort4 pkt;
                pkt.x = bf16b(p[kt][0]); pkt.y = bf16b(p[kt][1]);
                pkt.z = bf16b(p[kt][2]); pkt.w = bf16b(p[kt][3]);
                *(ushort4*)&Psw[l15 * 32 + kt * 16 + quad * 4] = pkt;
            }
            #pragma unroll
            for (int jt = 0; jt < 4; ++jt) {
                Oacc[jt][0] *= alpha; Oacc[jt][1] *= alpha;
                Oacc[jt][2] *= alpha; Oacc[jt][3] *= alpha;
            }

            short8 bP = *(const short8*)&Psw[l15 * 32 + quad * 8];
            #pragma unroll
            for (int jt = 0; jt < 4; ++jt) {
                short8 aV = *(const short8*)&Vtw[(jt * 16 + l15) * 32 + quad * 8];
                Oacc[jt] = __builtin_amdgcn_mfma_f32_16x16x32_bf16(aV, bP, Oacc[jt], 0, 0, 0);
            }
        }

        // cross-wave combine -> per-split partial (m, l, unnormalized O)
        __syncthreads();
        float* Om = (float*)smem;              // [4][16][64]
        float* Ml = (float*)(smem + 16384);    // [4][16]
        float* Ll = (float*)(smem + 16640);    // [4][16]
        #pragma unroll
        for (int jt = 0; jt < 4; ++jt)
            #pragma unroll
            for (int reg = 0; reg < 4; ++reg)
                Om[(w * 16 + l15) * 64 + jt * 16 + quad * 4 + reg] = Oacc[jt][reg];
        if (quad == 0) { Ml[w * 16 + l15] = mq; Ll[w * 16 + l15] = lq; }
        __syncthreads();

        const int pt = (h * 2 + gh) * NSPL + sp;   // partial-tile index
        const int d = tid & 63;
        #pragma unroll
        for (int k = 0; k < 4; ++k) {
            const int q = (tid >> 6) * 4 + k;
            float m0 = Ml[q], m1 = Ml[16 + q], m2 = Ml[32 + q], m3 = Ml[48 + q];
            float mM = fmaxf(fmaxf(m0, m1), fmaxf(m2, m3));
            float e0 = __expf(m0 - mM), e1 = __expf(m1 - mM);
            float e2 = __expf(m2 - mM), e3 = __expf(m3 - mM);
            float l = e0 * Ll[q] + e1 * Ll[16 + q] + e2 * Ll[32 + q] + e3 * Ll[48 + q];
            float o = e0 * Om[(q) * 64 + d]        + e1 * Om[(16 + q) * 64 + d]
                    + e2 * Om[(32 + q) * 64 + d]   + e3 * Om[(48 + q) * 64 + d];
            pO[(size_t)pt * 1024 + q * 64 + d] = o;
            if (d == 0) { pM[pt * 16 + q] = mM; pL[pt * 16 + q] = l; }
        }
    }
}

// ---------------------------------------------------------------------------
// Merge NSPL per-split partials into aout16 for the 32 global rows.
// 32 blocks x 256 threads; each block = one (head, gh) pair.
// ---------------------------------------------------------------------------
__global__ __launch_bounds__(256) void attn_combine(const float* __restrict__ pO,
                                                    const float* __restrict__ pM,
                                                    const float* __restrict__ pL,
                                                    unsigned short* __restrict__ aout16) {
    const int bid = blockIdx.x;         // 0..31
    const int h = bid >> 1, gh = bid & 1;
    const int base = (h * 2 + gh) * NSPL;
    #pragma unroll
    for (int k = 0; k < 4; ++k) {
        const int idx = threadIdx.x + k * 256;   // 0..1023
        const int q = idx >> 6, d = idx & 63;
        float mM = -1.0e30f;
        #pragma unroll
        for (int sp = 0; sp < NSPL; ++sp)
            mM = fmaxf(mM, pM[(base + sp) * 16 + q]);
        float l = 0.f, o = 0.f;
        #pragma unroll
        for (int sp = 0; sp < NSPL; ++sp) {
            const float e = __expf(pM[(base + sp) * 16 + q] - mM);
            l += e * pL[(base + sp) * 16 + q];
            o += e * pO[(size_t)(base + sp) * 1024 + q * 64 + d];
        }
        const int row = (gh * 16 + q) * 64;      // global token index
        aout16[(size_t)row * HID + h * HD + d] = bf16b(o / l);
    }
}

extern "C" void kernel_launch(void* const* d_in, const int* in_sizes, int n_in,
                              void* d_out, int out_size, void* d_ws, size_t ws_size,
                              hipStream_t stream) {
    const float* x    = (const float*)d_in[0];   // [2048,1024] fp32
    const float* Wqkv = (const float*)d_in[1];   // [3072,1024] fp32
    const float* Wout = (const float*)d_in[2];   // [1024,1024] fp32
    float* out = (float*)d_out;                  // [2048,1024] fp32

    unsigned short* x16    = (unsigned short*)d_ws;                 // 2048*1024
    unsigned short* wq16   = x16  + (size_t)SEQ * HID;              // 3072*1024
    unsigned short* wo16   = wq16 + (size_t)3 * HID * HID;          // 1024*1024
    unsigned short* qkv16  = wo16 + (size_t)HID * HID;              // 2048*3072
    unsigned short* aout16 = qkv16 + (size_t)SEQ * 3 * HID;         // 2048*1024
    float* pO = (float*)(aout16 + (size_t)SEQ * HID);               // 2*NH*NSPL*1024 f32
    float* pM = pO + (size_t)NH * 2 * NSPL * 1024;                  // 2*NH*NSPL*16 f32
    float* pL = pM + (size_t)NH * 2 * NSPL * 16;                    // 2*NH*NSPL*16 f32

    // 0) fp32 -> bf16 conversions
    cvt_bf16<<<dim3(1024), 256, 0, stream>>>(
        (const float4*)x, (const float4*)Wqkv, (const float4*)Wout,
        (ushort4*)x16, (ushort4*)wq16, (ushort4*)wo16);

    // 1) qkv16 = x16 @ wq16^T (bf16 out): 64x128 tile, BK=128, NW=8
    //    (512 threads) -> 768 blocks, 48KB LDS, 24 waves/CU (R9: -1.2us)
    gemm_bt16<64, 128, 128, 8, unsigned short><<<dim3(3 * HID / 128, SEQ / 64), 512, 0, stream>>>(
        x16, wq16, qkv16, SEQ, 3 * HID, HID);

    // 2) fused banded + split-K global attention, then split merge
    attn_fused<<<dim3(32 + 2 * NSPL, NH), 256, 0, stream>>>(
        qkv16, aout16, pO, pM, pL);
    attn_combine<<<dim3(32), 256, 0, stream>>>(pO, pM, pL, aout16);

    // 3) out = aout16 @ wo16^T (fp32 out): 64x64 tile, BK=128, NW=4 (R10
    //    regressed at NW=8 — frag grid fell to 2x1; revert to R4/R9 config)
    gemm_bt16<64, 64, 128, 4, float><<<dim3(HID / 64, SEQ / 64), 256, 0, stream>>>(
        aout16, wo16, out, SEQ, HID, HID);
}